// Round 10
// baseline (2551.948 us; speedup 1.0000x reference)
//
#include <hip/hip_runtime.h>
#include <hip/hip_bf16.h>

#define HID 4096
#define NEMBD 64
#define NBATCH 32
#define NTIME 64
#define NVOCAB 256
#define G4 16384

typedef __attribute__((ext_vector_type(4))) float f32x4;
typedef __attribute__((ext_vector_type(8))) short s16x8;

__device__ __forceinline__ unsigned short f2bf(float f) {
  union { float f; unsigned u; } v; v.f = f;
  unsigned u = v.u + 0x7FFFu + ((v.u >> 16) & 1u);
  return (unsigned short)(u >> 16);
}

// A-fragment packed offset for a [32 rows][4096 k] bf16 matrix, chunked by 32k:
// chunk*1024 + tile512*(row>=16) + lane*8 + elem, lane = (row&15) | (((k>>3)&3)<<4)
__device__ __forceinline__ int apoff(int b, int j) {
  return ((j >> 5) << 10) | ((b >> 4) << 9) |
         (((b & 15) | (((j >> 3) & 3) << 4)) << 3) | (j & 7);
}

// ---------------- one-pass coalesced pack + weight-norm scales -----------------------
// Block owns 64 consecutive RAW columns [c0, c0+64). Per k-row a 256B contiguous read
// (64 cols x 4B). Packs 4 fragment tiles per chunk; sumsq -> sc[j]=g[j]/||w_col||.
// four=1: gate-tiled dst (tile = ((c&4095)>>4)*4 + (c>>12)); four=0: flat (tile=c>>4).
__global__ void packs64_k(const float* __restrict__ src, const float* __restrict__ g,
                          unsigned short* __restrict__ dst, float* __restrict__ sc,
                          int N, int nch, int four) {
  const int c0 = blockIdx.x * 64;
  const int tid = threadIdx.x;
  const int cl = tid & 63, kr = tid >> 6;  // col-in-strip, k-row group 0..3
  const int c = c0 + cl;
  __shared__ unsigned short tile4[4][512];
  __shared__ float red[4][64];
  // dst tile index for the strip's 4 tiles (by sub-strip ti = cl>>4 for writes)
  const int wti = tid >> 6;          // tile sub-index for writeout
  const int wcol = c0 + wti * 16;    // first col of that tile
  const int wtile = four ? ((((wcol & 4095) >> 4) << 2) | (wcol >> 12)) : (wcol >> 4);
  unsigned short* wdst = dst + (size_t)wtile * nch * 512;
  float s = 0.f;
  const int ti = cl >> 4, col16 = cl & 15;
  for (int ch = 0; ch < nch; ++ch) {
#pragma unroll
    for (int sub = 0; sub < 8; ++sub) {
      int k32 = kr * 8 + sub;
      float v = src[(size_t)(ch * 32 + k32) * N + c];
      s += v * v;
      tile4[ti][(col16 | (kr << 4)) * 8 + sub] = f2bf(v);
    }
    __syncthreads();
    ((s16x8*)(wdst + (size_t)ch * 512))[tid & 63] = ((s16x8*)tile4[wti])[tid & 63];
    __syncthreads();
  }
  if (g) {
    red[kr][cl] = s;
    __syncthreads();
    if (tid < 64) {
      float tot = red[0][cl] + red[1][cl] + red[2][cl] + red[3][cl];
      sc[c0 + cl] = g[c0 + cl] / sqrtf(fmaxf(tot, 1e-12f));
    }
  }
}

// ---------------- embed X and pack x_t [32][64] into A-fragment order per t ----------
__global__ void xepack_k(const int* __restrict__ X, const float* __restrict__ embd,
                         unsigned short* __restrict__ xe) {
  int t = blockIdx.x;
  int tid = threadIdx.x;
  int l = tid & 63, tile = (tid >> 6) & 1, c2 = tid >> 7;
  int b = tile * 16 + (l & 15);
  int row = X[b * NTIME + t];
  int k0 = 32 * c2 + 8 * (l >> 4);
  size_t off = (size_t)t * 2048 + c2 * 1024 + tile * 512 + l * 8;
  for (int j = 0; j < 8; ++j) xe[off + j] = f2bf(embd[row * NEMBD + k0 + j]);
}

// ---------------- init states -------------------------------------------------------
__global__ void init_k(const float* __restrict__ S, float* __restrict__ cst,
                       float* __restrict__ hst, unsigned short* __restrict__ hpk) {
  int e = blockIdx.x * 256 + threadIdx.x;
  if (e < NBATCH * HID) {
    float c = S[e], h = S[NBATCH * HID + e];
    cst[e] = c; hst[e] = h;
    int b = e >> 12, j = e & 4095;
    hpk[apoff(b, j)] = f2bf(h);
  }
}

#define MFMA(a, b, c) __builtin_amdgcn_mfma_f32_16x16x32_bf16(a, b, c, 0, 0, 0)

// ---------------- phase 1 of step t: hm_raw = h@wmh_raw, m = xm*hm*scmx*scmh ---------
// full 8-chunk wmh preload (far stream), depth-2 rotation on hpk (L2-hot).
__global__ __launch_bounds__(1024, 4)
void ph1_k(const unsigned short* __restrict__ wmhp, const unsigned short* __restrict__ wmxp,
           const unsigned short* __restrict__ xe, const unsigned short* __restrict__ hpk,
           const float* __restrict__ scmh, const float* __restrict__ scmx,
           unsigned short* __restrict__ mpk, int t) {
  const int g = blockIdx.x;
  const int tid = threadIdx.x;
  const int w = tid >> 6, l = tid & 63;
  const int lo = l & 15, hi = l >> 4;

  __shared__ float part[16][32][16];
  __shared__ float xmS[32][16];

  const s16x8* wmh_g = (const s16x8*)(wmhp + (size_t)g * 128 * 512);
  const s16x8* wmx_g = (const s16x8*)(wmxp + (size_t)g * 2 * 512);
  const s16x8* hp = (const s16x8*)hpk;

  f32x4 a0 = {0.f, 0.f, 0.f, 0.f}, a1 = {0.f, 0.f, 0.f, 0.f};
  const int cb = w * 8;
  {
    s16x8 wbuf[8], pa[2], pb[2];
#pragma unroll
    for (int q = 0; q < 8; ++q) wbuf[q] = wmh_g[(cb + q) * 64 + l];
#pragma unroll
    for (int q = 0; q < 2; ++q) {
      pa[q] = hp[(cb + q) * 128 + l];
      pb[q] = hp[(cb + q) * 128 + 64 + l];
    }
#pragma unroll
    for (int q = 0; q < 8; ++q) {
      const int r2 = q & 1;
      s16x8 bf = wbuf[q], af = pa[r2], gf = pb[r2];
      if (q < 6) {
        pa[r2] = hp[(cb + q + 2) * 128 + l];
        pb[r2] = hp[(cb + q + 2) * 128 + 64 + l];
      }
      a0 = MFMA(af, bf, a0);
      a1 = MFMA(gf, bf, a1);
    }
  }
#pragma unroll
  for (int r = 0; r < 4; ++r) {
    part[w][4 * hi + r][lo] = a0[r];
    part[w][16 + 4 * hi + r][lo] = a1[r];
  }
  if (w == 0) {  // xm_raw = x_t @ wmx_raw (K=64)
    f32x4 x0 = {0.f, 0.f, 0.f, 0.f}, x1 = {0.f, 0.f, 0.f, 0.f};
    const s16x8* xep = (const s16x8*)(xe + (size_t)t * 2048);
#pragma unroll
    for (int c2 = 0; c2 < 2; ++c2) {
      s16x8 bf = wmx_g[c2 * 64 + l];
      x0 = MFMA(xep[c2 * 128 + l], bf, x0);
      x1 = MFMA(xep[c2 * 128 + 64 + l], bf, x1);
    }
#pragma unroll
    for (int r = 0; r < 4; ++r) {
      xmS[4 * hi + r][lo] = x0[r];
      xmS[16 + 4 * hi + r][lo] = x1[r];
    }
  }
  __syncthreads();
  if (tid < 512) {
    const int eb = tid >> 4, c = tid & 15;
    const int ej = g * 16 + c;
    float hm = 0.f;
#pragma unroll
    for (int k = 0; k < 16; ++k) hm += part[k][eb][c];
    mpk[apoff(eb, ej)] = f2bf(xmS[eb][c] * hm * (scmh[ej] * scmx[ej]));
  }
}

// ---------------- phase 2 of step t: z = scx*(x@wx) + sch*(m@wh) + b ; update --------
// wh (far) depth-8 rotation, mpk (L2-hot) depth-2.
__global__ __launch_bounds__(1024, 4)
void ph2_k(const unsigned short* __restrict__ whp, const unsigned short* __restrict__ wxp,
           const unsigned short* __restrict__ xe, const float* __restrict__ bias,
           const float* __restrict__ sch, const float* __restrict__ scx,
           const float* __restrict__ Mm, const unsigned short* __restrict__ mpk,
           unsigned short* __restrict__ hpk, float* __restrict__ cst,
           float* __restrict__ hst, unsigned short* __restrict__ hflat,
           float* __restrict__ out, int t) {
  const int g = blockIdx.x;
  const int tid = threadIdx.x;
  const int w = tid >> 6, l = tid & 63;
  const int lo = l & 15, hi = l >> 4;
  const int gate = w & 3, ks = w >> 2;

  __shared__ float part[16][32][16];
  __shared__ float xpart[4][32][16];

  const s16x8* wh_w = (const s16x8*)(whp + (size_t)(g * 4 + gate) * 128 * 512);
  const s16x8* wx_w = (const s16x8*)(wxp + (size_t)(g * 4 + gate) * 2 * 512);
  const s16x8* mp = (const s16x8*)mpk;

  f32x4 z0 = {0.f, 0.f, 0.f, 0.f}, z1 = {0.f, 0.f, 0.f, 0.f};
  const int cb = ks * 32;
  {
    s16x8 wbuf[8], pa[2], pb[2];
#pragma unroll
    for (int q = 0; q < 8; ++q) wbuf[q] = wh_w[(cb + q) * 64 + l];
#pragma unroll
    for (int q = 0; q < 2; ++q) {
      pa[q] = mp[(cb + q) * 128 + l];
      pb[q] = mp[(cb + q) * 128 + 64 + l];
    }
#pragma unroll
    for (int q = 0; q < 32; ++q) {
      const int r8 = q & 7, r2 = q & 1;
      s16x8 bf = wbuf[r8], af = pa[r2], gf = pb[r2];
      if (q < 24) wbuf[r8] = wh_w[(cb + q + 8) * 64 + l];
      if (q < 30) {
        pa[r2] = mp[(cb + q + 2) * 128 + l];
        pb[r2] = mp[(cb + q + 2) * 128 + 64 + l];
      }
      z0 = MFMA(af, bf, z0);
      z1 = MFMA(gf, bf, z1);
    }
  }
  if (ks == 0) {  // x @ wx_raw contribution (K=64), kept separate for scx scaling
    f32x4 x0 = {0.f, 0.f, 0.f, 0.f}, x1 = {0.f, 0.f, 0.f, 0.f};
    const s16x8* xep = (const s16x8*)(xe + (size_t)t * 2048);
#pragma unroll
    for (int c2 = 0; c2 < 2; ++c2) {
      s16x8 bf = wx_w[c2 * 64 + l];
      x0 = MFMA(xep[c2 * 128 + l], bf, x0);
      x1 = MFMA(xep[c2 * 128 + 64 + l], bf, x1);
    }
#pragma unroll
    for (int r = 0; r < 4; ++r) {
      xpart[gate][4 * hi + r][lo] = x0[r];
      xpart[gate][16 + 4 * hi + r][lo] = x1[r];
    }
  }
#pragma unroll
  for (int r = 0; r < 4; ++r) {
    part[w][4 * hi + r][lo] = z0[r];
    part[w][16 + 4 * hi + r][lo] = z1[r];
  }
  __syncthreads();
  if (tid < 512) {
    const int eb = tid >> 4, c = tid & 15;
    const int ej = g * 16 + c;
    float zh, iv, fv, ov, uv;
    zh = part[0][eb][c] + part[4][eb][c] + part[8][eb][c] + part[12][eb][c];
    iv = zh * sch[ej] + xpart[0][eb][c] * scx[ej] + bias[ej];
    zh = part[1][eb][c] + part[5][eb][c] + part[9][eb][c] + part[13][eb][c];
    fv = zh * sch[4096 + ej] + xpart[1][eb][c] * scx[4096 + ej] + bias[4096 + ej];
    zh = part[2][eb][c] + part[6][eb][c] + part[10][eb][c] + part[14][eb][c];
    ov = zh * sch[8192 + ej] + xpart[2][eb][c] * scx[8192 + ej] + bias[8192 + ej];
    zh = part[3][eb][c] + part[7][eb][c] + part[11][eb][c] + part[15][eb][c];
    uv = zh * sch[12288 + ej] + xpart[3][eb][c] * scx[12288 + ej] + bias[12288 + ej];
    iv = 1.f / (1.f + __expf(-iv));
    fv = 1.f / (1.f + __expf(-fv));
    ov = 1.f / (1.f + __expf(-ov));
    uv = tanhf(uv);
    size_t sj = (size_t)eb * HID + ej;
    float cp = cst[sj], hpv = hst[sj];
    float ct = fv * cp + iv * uv;
    float ht = ov * tanhf(ct);
    float mt = Mm[eb * NTIME + t];
    float cn = ct * mt + cp * (1.f - mt);
    float hn = ht * mt + hpv * (1.f - mt);
    cst[sj] = cn;
    hst[sj] = hn;
    out[((size_t)t * NBATCH + eb) * HID + ej] = cn;
    unsigned short hb = f2bf(hn);
    // packed A-fragment write for logits: tile = eb*4 + (t>>4), row-in-tile = t&15
    {
      int tle = eb * 4 + (t >> 4);
      int r16 = t & 15;
      int kk2 = ej & 31;
      int lane2 = r16 | (((kk2 >> 3) & 3) << 4);
      hflat[(size_t)tle * 65536 + (size_t)(ej >> 5) * 512 + lane2 * 8 + (kk2 & 7)] = hb;
    }
    hpk[apoff(eb, ej)] = hb;
    if (t == NTIME - 1) {
      out[(size_t)NTIME * NBATCH * HID + sj] = cn;
      out[(size_t)NTIME * NBATCH * HID + NBATCH * HID + sj] = hn;
    }
  }
}

// ---------------- logits = hflat @ w_out + b_out, packed-A ([2048,4096]x[4096,256]) --
__global__ __launch_bounds__(256)
void logits_k(const unsigned short* __restrict__ hpA,
              const unsigned short* __restrict__ woutp,
              const float* __restrict__ bout, float* __restrict__ out) {
  int tle = blockIdx.x >> 1, ch = blockIdx.x & 1;
  int tid = threadIdx.x, w = tid >> 6, l = tid & 63;
  int lo = l & 15, hi = l >> 4;
  const s16x8* ap = (const s16x8*)(hpA + (size_t)tle * 65536);
  const s16x8* wp = (const s16x8*)woutp;
  f32x4 acc[2] = {{0.f,0.f,0.f,0.f},{0.f,0.f,0.f,0.f}};
  const int nt0 = ch * 8 + w * 2;
#pragma unroll 4
  for (int c = 0; c < 128; ++c) {
    s16x8 af = ap[c * 64 + l];
    acc[0] = MFMA(af, wp[((nt0 + 0) * 128 + c) * 64 + l], acc[0]);
    acc[1] = MFMA(af, wp[((nt0 + 1) * 128 + c) * 64 + l], acc[1]);
  }
  int r0 = tle * 16;
#pragma unroll
  for (int q = 0; q < 2; ++q) {
    int col = (nt0 + q) * 16 + lo;
    float bo = bout[col];
#pragma unroll
    for (int r = 0; r < 4; ++r)
      out[(size_t)(r0 + 4 * hi + r) * NVOCAB + col] = acc[q][r] + bo;
  }
}

extern "C" void kernel_launch(void* const* d_in, const int* in_sizes, int n_in,
                              void* d_out, int out_size, void* d_ws, size_t ws_size,
                              hipStream_t stream) {
  const int*   X    = (const int*)d_in[0];
  const float* Mm   = (const float*)d_in[1];
  const float* S    = (const float*)d_in[2];
  const float* embd = (const float*)d_in[3];
  const float* wx   = (const float*)d_in[4];
  const float* wh   = (const float*)d_in[5];
  const float* wmx  = (const float*)d_in[6];
  const float* wmh  = (const float*)d_in[7];
  const float* b    = (const float*)d_in[8];
  const float* gx   = (const float*)d_in[9];
  const float* gh   = (const float*)d_in[10];
  const float* gmx  = (const float*)d_in[11];
  const float* gmh  = (const float*)d_in[12];
  const float* wout = (const float*)d_in[13];
  const float* bout = (const float*)d_in[14];
  float* out = (float*)d_out;
  char* ws = (char*)d_ws;

  size_t cur = 0;
  auto alloc = [&](size_t bytes) { size_t o = cur; cur += (bytes + 255) & ~size_t(255); return o; };
  unsigned short* WHP   = (unsigned short*)(ws + alloc((size_t)1024 * 128 * 512 * 2)); // 128MB
  unsigned short* WMHP  = (unsigned short*)(ws + alloc((size_t)256 * 128 * 512 * 2));  // 32MB
  unsigned short* WXP   = (unsigned short*)(ws + alloc((size_t)1024 * 2 * 512 * 2));   // 2MB
  unsigned short* WMXP  = (unsigned short*)(ws + alloc((size_t)256 * 2 * 512 * 2));    // 0.5MB
  unsigned short* WOUTP = (unsigned short*)(ws + alloc((size_t)16 * 128 * 512 * 2));   // 2MB
  unsigned short* XE    = (unsigned short*)(ws + alloc((size_t)64 * 2048 * 2));        // 256KB
  unsigned short* MPK   = (unsigned short*)(ws + alloc((size_t)32 * 4096 * 2));        // 256KB
  unsigned short* HPK   = (unsigned short*)(ws + alloc((size_t)32 * 4096 * 2));        // 256KB
  float* CST            = (float*)(ws + alloc((size_t)32 * 4096 * 4));
  float* HST            = (float*)(ws + alloc((size_t)32 * 4096 * 4));
  unsigned short* HFLAT = (unsigned short*)(ws + alloc((size_t)2048 * 4096 * 2));      // 16MB
  float* SCH            = (float*)(ws + alloc((size_t)16384 * 4));
  float* SCX            = (float*)(ws + alloc((size_t)16384 * 4));
  float* SCMH           = (float*)(ws + alloc((size_t)4096 * 4));
  float* SCMX           = (float*)(ws + alloc((size_t)4096 * 4));
  (void)ws_size; (void)in_sizes; (void)n_in; (void)out_size;

  // one-pass coalesced: pack raw weights to bf16 fragments + weight-norm scales
  packs64_k<<<256, 256, 0, stream>>>(wh,   gh,  WHP,   SCH,  G4,    128, 1);
  packs64_k<<<64,  256, 0, stream>>>(wmh,  gmh, WMHP,  SCMH, HID,   128, 0);
  packs64_k<<<256, 256, 0, stream>>>(wx,   gx,  WXP,   SCX,  G4,    2,   1);
  packs64_k<<<64,  256, 0, stream>>>(wmx,  gmx, WMXP,  SCMX, HID,   2,   0);
  packs64_k<<<4,   256, 0, stream>>>(wout, nullptr, WOUTP, nullptr, NVOCAB, 128, 0);

  xepack_k<<<64, 256, 0, stream>>>(X, embd, XE);
  init_k<<<512, 256, 0, stream>>>(S, CST, HST, HPK);

  // 64 steps, 2 kernels per step — stream ordering replaces the grid barrier
  for (int t = 0; t < NTIME; ++t) {
    ph1_k<<<256, 1024, 0, stream>>>(WMHP, WMXP, XE, HPK, SCMH, SCMX, MPK, t);
    ph2_k<<<256, 1024, 0, stream>>>(WHP, WXP, XE, b, SCH, SCX, Mm, MPK, HPK, CST, HST,
                                    HFLAT, out, t);
  }

  logits_k<<<256, 256, 0, stream>>>(HFLAT, WOUTP, bout,
                                    out + (size_t)NTIME * NBATCH * HID + 2 * NBATCH * HID);
}

// Round 11
// 2406.505 us; speedup vs baseline: 1.0604x; 1.0604x over previous
//
#include <hip/hip_runtime.h>
#include <hip/hip_bf16.h>

#define HID 4096
#define NEMBD 64
#define NBATCH 32
#define NTIME 64
#define NVOCAB 256
#define G4 16384

typedef __attribute__((ext_vector_type(4))) float f32x4;
typedef __attribute__((ext_vector_type(8))) short s16x8;

__device__ __forceinline__ unsigned short f2bf(float f) {
  union { float f; unsigned u; } v; v.f = f;
  unsigned u = v.u + 0x7FFFu + ((v.u >> 16) & 1u);
  return (unsigned short)(u >> 16);
}

// A-fragment packed offset for a [32 rows][4096 k] bf16 matrix, chunked by 32k:
// chunk*1024 + tile512*(row>=16) + lane*8 + elem, lane = (row&15) | (((k>>3)&3)<<4)
__device__ __forceinline__ int apoff(int b, int j) {
  return ((j >> 5) << 10) | ((b >> 4) << 9) |
         (((b & 15) | (((j >> 3) & 3) << 4)) << 3) | (j & 7);
}

// ---------------- fused one-pass: pack RAW fp32 [K][N] strip into bf16 B-fragments ---
// and produce weight-norm scale sc[j] = g[j]/sqrt(sum_k w[k][j]^2) (scale applied at
// runtime in the consumers). Block bid: colbase=(bid&3)*Cw+(bid>>S)*16; K = nch*32.
__global__ void packs_k(const float* __restrict__ src, const float* __restrict__ g,
                        unsigned short* __restrict__ dst, float* __restrict__ sc,
                        int N, int Cw, int S, int nch) {
  int bid = blockIdx.x;
  int colbase = (bid & 3) * Cw + (bid >> S) * 16;
  size_t dstbase = (size_t)bid * nch * 512;
  __shared__ unsigned short tile[512];
  __shared__ float red[16][16];
  int tid = threadIdx.x;
  int col16 = tid & 15, kk = tid >> 4;  // kk in 0..15
  float s = 0.f;
  for (int c = 0; c < nch; ++c) {
    float v0 = src[(size_t)(c * 32 + kk) * N + colbase + col16];
    float v1 = src[(size_t)(c * 32 + kk + 16) * N + colbase + col16];
    s += v0 * v0 + v1 * v1;
    int l0 = col16 | (((kk >> 3) & 3) << 4);
    int l1 = col16 | ((((kk + 16) >> 3) & 3) << 4);
    tile[l0 * 8 + (kk & 7)] = f2bf(v0);
    tile[l1 * 8 + (kk & 7)] = f2bf(v1);
    __syncthreads();
    if (tid < 64)
      ((s16x8*)(dst + dstbase + (size_t)c * 512))[tid] = ((s16x8*)tile)[tid];
    __syncthreads();
  }
  if (g) {
    red[kk][col16] = s;
    __syncthreads();
    if (tid < 16) {
      float tot = 0.f;
#pragma unroll
      for (int q = 0; q < 16; ++q) tot += red[q][tid];
      sc[colbase + tid] = g[colbase + tid] / sqrtf(fmaxf(tot, 1e-12f));
    }
  }
}

// ---------------- embed X and pack x_t [32][64] into A-fragment order per t ----------
__global__ void xepack_k(const int* __restrict__ X, const float* __restrict__ embd,
                         unsigned short* __restrict__ xe) {
  int t = blockIdx.x;
  int tid = threadIdx.x;
  int l = tid & 63, tile = (tid >> 6) & 1, c2 = tid >> 7;
  int b = tile * 16 + (l & 15);
  int row = X[b * NTIME + t];
  int k0 = 32 * c2 + 8 * (l >> 4);
  size_t off = (size_t)t * 2048 + c2 * 1024 + tile * 512 + l * 8;
  for (int j = 0; j < 8; ++j) xe[off + j] = f2bf(embd[row * NEMBD + k0 + j]);
}

// ---------------- init states -------------------------------------------------------
__global__ void init_k(const float* __restrict__ S, float* __restrict__ cst,
                       float* __restrict__ hst, unsigned short* __restrict__ hpk) {
  int e = blockIdx.x * 256 + threadIdx.x;
  if (e < NBATCH * HID) {
    float c = S[e], h = S[NBATCH * HID + e];
    cst[e] = c; hst[e] = h;
    int b = e >> 12, j = e & 4095;
    hpk[apoff(b, j)] = f2bf(h);
  }
}

#define MFMA(a, b, c) __builtin_amdgcn_mfma_f32_16x16x32_bf16(a, b, c, 0, 0, 0)

// ---------------- phase 1 of step t: hm_raw = h@wmh_raw, m = xm*hm*scmx*scmh ---------
__global__ __launch_bounds__(1024, 4)
void ph1_k(const unsigned short* __restrict__ wmhp, const unsigned short* __restrict__ wmxp,
           const unsigned short* __restrict__ xe, const unsigned short* __restrict__ hpk,
           const float* __restrict__ scmh, const float* __restrict__ scmx,
           unsigned short* __restrict__ mpk, int t) {
  const int g = blockIdx.x;
  const int tid = threadIdx.x;
  const int w = tid >> 6, l = tid & 63;
  const int lo = l & 15, hi = l >> 4;

  __shared__ float part[16][32][16];
  __shared__ float xmS[32][16];

  const s16x8* wmh_g = (const s16x8*)(wmhp + (size_t)g * 128 * 512);
  const s16x8* wmx_g = (const s16x8*)(wmxp + (size_t)g * 2 * 512);
  const s16x8* hp = (const s16x8*)hpk;

  f32x4 a0 = {0.f, 0.f, 0.f, 0.f}, a1 = {0.f, 0.f, 0.f, 0.f};
  const int cb = w * 8;
  {
    s16x8 wbuf[4], pa[4], pb[4];
#pragma unroll
    for (int q = 0; q < 4; ++q) {
      wbuf[q] = wmh_g[(cb + q) * 64 + l];
      pa[q] = hp[(cb + q) * 128 + l];
      pb[q] = hp[(cb + q) * 128 + 64 + l];
    }
#pragma unroll
    for (int q = 0; q < 8; ++q) {
      const int r = q & 3;
      s16x8 bf = wbuf[r], af = pa[r], gf = pb[r];
      if (q < 4) {
        wbuf[r] = wmh_g[(cb + q + 4) * 64 + l];
        pa[r] = hp[(cb + q + 4) * 128 + l];
        pb[r] = hp[(cb + q + 4) * 128 + 64 + l];
      }
      a0 = MFMA(af, bf, a0);
      a1 = MFMA(gf, bf, a1);
    }
  }
#pragma unroll
  for (int r = 0; r < 4; ++r) {
    part[w][4 * hi + r][lo] = a0[r];
    part[w][16 + 4 * hi + r][lo] = a1[r];
  }
  if (w == 0) {  // xm_raw = x_t @ wmx_raw (K=64)
    f32x4 x0 = {0.f, 0.f, 0.f, 0.f}, x1 = {0.f, 0.f, 0.f, 0.f};
    const s16x8* xep = (const s16x8*)(xe + (size_t)t * 2048);
#pragma unroll
    for (int c2 = 0; c2 < 2; ++c2) {
      s16x8 bf = wmx_g[c2 * 64 + l];
      x0 = MFMA(xep[c2 * 128 + l], bf, x0);
      x1 = MFMA(xep[c2 * 128 + 64 + l], bf, x1);
    }
#pragma unroll
    for (int r = 0; r < 4; ++r) {
      xmS[4 * hi + r][lo] = x0[r];
      xmS[16 + 4 * hi + r][lo] = x1[r];
    }
  }
  __syncthreads();
  if (tid < 512) {
    const int eb = tid >> 4, c = tid & 15;
    const int ej = g * 16 + c;
    float hm = 0.f;
#pragma unroll
    for (int k = 0; k < 16; ++k) hm += part[k][eb][c];
    mpk[apoff(eb, ej)] = f2bf(xmS[eb][c] * hm * (scmh[ej] * scmx[ej]));
  }
}

// ---------------- phase 2 of step t: z = scx*(x@wx) + sch*(m@wh) + b ; update --------
__global__ __launch_bounds__(1024, 4)
void ph2_k(const unsigned short* __restrict__ whp, const unsigned short* __restrict__ wxp,
           const unsigned short* __restrict__ xe, const float* __restrict__ bias,
           const float* __restrict__ sch, const float* __restrict__ scx,
           const float* __restrict__ Mm, const unsigned short* __restrict__ mpk,
           unsigned short* __restrict__ hpk, float* __restrict__ cst,
           float* __restrict__ hst, unsigned short* __restrict__ hflat,
           float* __restrict__ out, int t) {
  const int g = blockIdx.x;
  const int tid = threadIdx.x;
  const int w = tid >> 6, l = tid & 63;
  const int lo = l & 15, hi = l >> 4;
  const int gate = w & 3, ks = w >> 2;

  __shared__ float part[16][32][16];
  __shared__ float xpart[4][32][16];

  const s16x8* wh_w = (const s16x8*)(whp + (size_t)(g * 4 + gate) * 128 * 512);
  const s16x8* wx_w = (const s16x8*)(wxp + (size_t)(g * 4 + gate) * 2 * 512);
  const s16x8* mp = (const s16x8*)mpk;

  f32x4 z0 = {0.f, 0.f, 0.f, 0.f}, z1 = {0.f, 0.f, 0.f, 0.f};
  const int cb = ks * 32;
  {
    s16x8 wbuf[4], pa[4], pb[4];
#pragma unroll
    for (int q = 0; q < 4; ++q) {
      wbuf[q] = wh_w[(cb + q) * 64 + l];
      pa[q] = mp[(cb + q) * 128 + l];
      pb[q] = mp[(cb + q) * 128 + 64 + l];
    }
#pragma unroll
    for (int q = 0; q < 32; ++q) {
      const int r = q & 3;
      s16x8 bf = wbuf[r], af = pa[r], gf = pb[r];
      if (q < 28) {
        wbuf[r] = wh_w[(cb + q + 4) * 64 + l];
        pa[r] = mp[(cb + q + 4) * 128 + l];
        pb[r] = mp[(cb + q + 4) * 128 + 64 + l];
      }
      z0 = MFMA(af, bf, z0);
      z1 = MFMA(gf, bf, z1);
    }
  }
  if (ks == 0) {  // x @ wx_raw contribution (K=64), kept separate for scx scaling
    f32x4 x0 = {0.f, 0.f, 0.f, 0.f}, x1 = {0.f, 0.f, 0.f, 0.f};
    const s16x8* xep = (const s16x8*)(xe + (size_t)t * 2048);
#pragma unroll
    for (int c2 = 0; c2 < 2; ++c2) {
      s16x8 bf = wx_w[c2 * 64 + l];
      x0 = MFMA(xep[c2 * 128 + l], bf, x0);
      x1 = MFMA(xep[c2 * 128 + 64 + l], bf, x1);
    }
#pragma unroll
    for (int r = 0; r < 4; ++r) {
      xpart[gate][4 * hi + r][lo] = x0[r];
      xpart[gate][16 + 4 * hi + r][lo] = x1[r];
    }
  }
#pragma unroll
  for (int r = 0; r < 4; ++r) {
    part[w][4 * hi + r][lo] = z0[r];
    part[w][16 + 4 * hi + r][lo] = z1[r];
  }
  __syncthreads();
  if (tid < 512) {
    const int eb = tid >> 4, c = tid & 15;
    const int ej = g * 16 + c;
    float zh, iv, fv, ov, uv;
    zh = part[0][eb][c] + part[4][eb][c] + part[8][eb][c] + part[12][eb][c];
    iv = zh * sch[ej] + xpart[0][eb][c] * scx[ej] + bias[ej];
    zh = part[1][eb][c] + part[5][eb][c] + part[9][eb][c] + part[13][eb][c];
    fv = zh * sch[4096 + ej] + xpart[1][eb][c] * scx[4096 + ej] + bias[4096 + ej];
    zh = part[2][eb][c] + part[6][eb][c] + part[10][eb][c] + part[14][eb][c];
    ov = zh * sch[8192 + ej] + xpart[2][eb][c] * scx[8192 + ej] + bias[8192 + ej];
    zh = part[3][eb][c] + part[7][eb][c] + part[11][eb][c] + part[15][eb][c];
    uv = zh * sch[12288 + ej] + xpart[3][eb][c] * scx[12288 + ej] + bias[12288 + ej];
    iv = 1.f / (1.f + __expf(-iv));
    fv = 1.f / (1.f + __expf(-fv));
    ov = 1.f / (1.f + __expf(-ov));
    uv = tanhf(uv);
    size_t sj = (size_t)eb * HID + ej;
    float cp = cst[sj], hpv = hst[sj];
    float ct = fv * cp + iv * uv;
    float ht = ov * tanhf(ct);
    float mt = Mm[eb * NTIME + t];
    float cn = ct * mt + cp * (1.f - mt);
    float hn = ht * mt + hpv * (1.f - mt);
    cst[sj] = cn;
    hst[sj] = hn;
    out[((size_t)t * NBATCH + eb) * HID + ej] = cn;
    unsigned short hb = f2bf(hn);
    // packed A-fragment write for logits: tile = eb*4 + (t>>4), row-in-tile = t&15
    {
      int tle = eb * 4 + (t >> 4);
      int r16 = t & 15;
      int kk2 = ej & 31;
      int lane2 = r16 | (((kk2 >> 3) & 3) << 4);
      hflat[(size_t)tle * 65536 + (size_t)(ej >> 5) * 512 + lane2 * 8 + (kk2 & 7)] = hb;
    }
    hpk[apoff(eb, ej)] = hb;
    if (t == NTIME - 1) {
      out[(size_t)NTIME * NBATCH * HID + sj] = cn;
      out[(size_t)NTIME * NBATCH * HID + NBATCH * HID + sj] = hn;
    }
  }
}

// ---------------- logits = hflat @ w_out + b_out, packed-A ([2048,4096]x[4096,256]) --
__global__ __launch_bounds__(256)
void logits_k(const unsigned short* __restrict__ hpA,
              const unsigned short* __restrict__ woutp,
              const float* __restrict__ bout, float* __restrict__ out) {
  int tle = blockIdx.x >> 1, ch = blockIdx.x & 1;
  int tid = threadIdx.x, w = tid >> 6, l = tid & 63;
  int lo = l & 15, hi = l >> 4;
  const s16x8* ap = (const s16x8*)(hpA + (size_t)tle * 65536);
  const s16x8* wp = (const s16x8*)woutp;
  f32x4 acc[2] = {{0.f,0.f,0.f,0.f},{0.f,0.f,0.f,0.f}};
  const int nt0 = ch * 8 + w * 2;
#pragma unroll 4
  for (int c = 0; c < 128; ++c) {
    s16x8 af = ap[c * 64 + l];
    acc[0] = MFMA(af, wp[((nt0 + 0) * 128 + c) * 64 + l], acc[0]);
    acc[1] = MFMA(af, wp[((nt0 + 1) * 128 + c) * 64 + l], acc[1]);
  }
  int r0 = tle * 16;
#pragma unroll
  for (int q = 0; q < 2; ++q) {
    int col = (nt0 + q) * 16 + lo;
    float bo = bout[col];
#pragma unroll
    for (int r = 0; r < 4; ++r)
      out[(size_t)(r0 + 4 * hi + r) * NVOCAB + col] = acc[q][r] + bo;
  }
}

extern "C" void kernel_launch(void* const* d_in, const int* in_sizes, int n_in,
                              void* d_out, int out_size, void* d_ws, size_t ws_size,
                              hipStream_t stream) {
  const int*   X    = (const int*)d_in[0];
  const float* Mm   = (const float*)d_in[1];
  const float* S    = (const float*)d_in[2];
  const float* embd = (const float*)d_in[3];
  const float* wx   = (const float*)d_in[4];
  const float* wh   = (const float*)d_in[5];
  const float* wmx  = (const float*)d_in[6];
  const float* wmh  = (const float*)d_in[7];
  const float* b    = (const float*)d_in[8];
  const float* gx   = (const float*)d_in[9];
  const float* gh   = (const float*)d_in[10];
  const float* gmx  = (const float*)d_in[11];
  const float* gmh  = (const float*)d_in[12];
  const float* wout = (const float*)d_in[13];
  const float* bout = (const float*)d_in[14];
  float* out = (float*)d_out;
  char* ws = (char*)d_ws;

  size_t cur = 0;
  auto alloc = [&](size_t bytes) { size_t o = cur; cur += (bytes + 255) & ~size_t(255); return o; };
  unsigned short* WHP   = (unsigned short*)(ws + alloc((size_t)1024 * 128 * 512 * 2)); // 128MB
  unsigned short* WMHP  = (unsigned short*)(ws + alloc((size_t)256 * 128 * 512 * 2));  // 32MB
  unsigned short* WXP   = (unsigned short*)(ws + alloc((size_t)1024 * 2 * 512 * 2));   // 2MB
  unsigned short* WMXP  = (unsigned short*)(ws + alloc((size_t)256 * 2 * 512 * 2));    // 0.5MB
  unsigned short* WOUTP = (unsigned short*)(ws + alloc((size_t)16 * 128 * 512 * 2));   // 2MB
  unsigned short* XE    = (unsigned short*)(ws + alloc((size_t)64 * 2048 * 2));        // 256KB
  unsigned short* MPK   = (unsigned short*)(ws + alloc((size_t)32 * 4096 * 2));        // 256KB
  unsigned short* HPK   = (unsigned short*)(ws + alloc((size_t)32 * 4096 * 2));        // 256KB
  float* CST            = (float*)(ws + alloc((size_t)32 * 4096 * 4));
  float* HST            = (float*)(ws + alloc((size_t)32 * 4096 * 4));
  unsigned short* HFLAT = (unsigned short*)(ws + alloc((size_t)2048 * 4096 * 2));      // 16MB
  float* SCH            = (float*)(ws + alloc((size_t)16384 * 4));
  float* SCX            = (float*)(ws + alloc((size_t)16384 * 4));
  float* SCMH           = (float*)(ws + alloc((size_t)4096 * 4));
  float* SCMX           = (float*)(ws + alloc((size_t)4096 * 4));
  (void)ws_size; (void)in_sizes; (void)n_in; (void)out_size;

  // one-pass: pack raw weights to bf16 fragments + compute weight-norm scales
  packs_k<<<1024, 256, 0, stream>>>(wh,   gh,  WHP,   SCH,  G4,    4096, 2, 128);
  packs_k<<<256,  256, 0, stream>>>(wmh,  gmh, WMHP,  SCMH, HID,   0,    0, 128);
  packs_k<<<1024, 256, 0, stream>>>(wx,   gx,  WXP,   SCX,  G4,    4096, 2, 2);
  packs_k<<<256,  256, 0, stream>>>(wmx,  gmx, WMXP,  SCMX, HID,   0,    0, 2);
  packs_k<<<16,   256, 0, stream>>>(wout, nullptr, WOUTP, nullptr, NVOCAB, 0, 0, 128);

  xepack_k<<<64, 256, 0, stream>>>(X, embd, XE);
  init_k<<<512, 256, 0, stream>>>(S, CST, HST, HPK);

  // 64 steps, 2 kernels per step — stream ordering replaces the grid barrier
  for (int t = 0; t < NTIME; ++t) {
    ph1_k<<<256, 1024, 0, stream>>>(WMHP, WMXP, XE, HPK, SCMH, SCMX, MPK, t);
    ph2_k<<<256, 1024, 0, stream>>>(WHP, WXP, XE, b, SCH, SCX, Mm, MPK, HPK, CST, HST,
                                    HFLAT, out, t);
  }

  logits_k<<<256, 256, 0, stream>>>(HFLAT, WOUTP, bout,
                                    out + (size_t)NTIME * NBATCH * HID + 2 * NBATCH * HID);
}